// Round 4
// baseline (2900.971 us; speedup 1.0000x reference)
//
#include <hip/hip_runtime.h>

#define B_ 128
#define T_ 256
#define L_ 4
#define DC_ 128
#define DW_ 128
#define H_ 256
#define V_ 6000
#define Z4_ 1024   // 4*H
#define S_ 4       // blocks per group (z-column split)
#define R_ 2       // batch rows per group
#define G_ 64      // groups = B/R
#define NEGF -1e30f

// d_ws layout (bytes). Stamps live inside data words — no flags, no memset.
#define WS_VTAB  4096                          // V*L*DW f32 = 12,288,000
#define WS_NH    (WS_VTAB + V_*L_*DW_*4)       // u64 [2][G][R][H]      = 512 KB
#define WS_PP    (WS_NH + (size_t)2*G_*R_*H_*8)// u64 [2][G][S][R][128] = 1 MB
#define WS_XCC   (WS_PP + (size_t)2*G_*S_*R_*128*8) // u64 [S_][G_] = 2 KB

#define XCC_MAGIC 0xC0FFEE01u

typedef unsigned long long u64w;

__device__ __forceinline__ float sigm(float x) { return 1.0f / (1.0f + expf(-x)); }
__device__ __forceinline__ u64w packw(float v, unsigned stamp) {
  return ((u64w)__float_as_uint(v) << 32) | (u64w)stamp;
}
__device__ __forceinline__ void pub64(u64w* p, float v, unsigned stamp) {
  __hip_atomic_store(p, packw(v, stamp), __ATOMIC_RELAXED, __HIP_MEMORY_SCOPE_AGENT);
}
__device__ __forceinline__ void pub64u(u64w* p, unsigned v, unsigned stamp) {
  u64w w = ((u64w)v << 32) | (u64w)stamp;
  __hip_atomic_store(p, w, __ATOMIC_RELAXED, __HIP_MEMORY_SCOPE_AGENT);
}
__device__ __forceinline__ u64w ld64(const u64w* p) {
  return __hip_atomic_load(p, __ATOMIC_RELAXED, __HIP_MEMORY_SCOPE_AGENT);
}
// XCD-local L2 poll load: bypass L1 (sc0) but NOT L2 (no sc1). Issue-only —
// caller must vm_wait0() before reading the result (rule: sched_barrier(0)
// after the waitcnt, else MFMA/VALU consumers get hoisted past it).
__device__ __forceinline__ u64w ld64_l2_issue(const u64w* p) {
  u64w r;
  asm volatile("global_load_dwordx2 %0, %1, off sc0" : "=&v"(r) : "v"(p));
  return r;
}
__device__ __forceinline__ void vm_wait0() {
  asm volatile("s_waitcnt vmcnt(0)" ::: "memory");
  __builtin_amdgcn_sched_barrier(0);
}
__device__ __forceinline__ float hi32(u64w w) {
  return __uint_as_float((unsigned)(w >> 32));
}
// wave-broadcast from lane l via v_readlane (result lands in an SGPR — no VGPR cost)
__device__ __forceinline__ float bcast(float v, int l) {
  return __int_as_float(__builtin_amdgcn_readlane(__float_as_int(v), l));
}
__device__ __forceinline__ int amax4(const float* sc) {   // first-max-wins (jnp.argmax)
  float bs = sc[0]; int bw = 0;
  if (sc[1] > bs) { bs = sc[1]; bw = 1; }
  if (sc[2] > bs) { bs = sc[2]; bw = 2; }
  if (sc[3] > bs) { bs = sc[3]; bw = 3; }
  return bw;
}
__device__ __forceinline__ float invlen(int w) {
  return (w == 0) ? 1.0f : (w == 1) ? 0.5f : (w == 2) ? (1.0f / 3.0f) : 0.25f;
}

// ------------------------------------------------------------------
// Kernel 1: vocab composition table (unchanged — verified).
// ------------------------------------------------------------------
__global__ __launch_bounds__(512) void vtab_kernel(
    const float* __restrict__ char_emb, const float* __restrict__ reset_W,
    const float* __restrict__ reset_b, const float* __restrict__ com_W,
    const float* __restrict__ com_b, float* __restrict__ Vtab)
{
  const int v = blockIdx.x;
  const int tid = threadIdx.x;
  const int w = tid >> 7;
  const int e = tid & 127;
  __shared__ float emb[DC_];
  __shared__ float ge[L_][DC_];
  if (tid < DC_) emb[tid] = char_emb[v * DC_ + tid];
  __syncthreads();
  float acc = reset_b[w * DC_ + e];
  const float* W = reset_W + (size_t)w * DC_ * DC_;
  #pragma unroll 8
  for (int k = 0; k < DC_; ++k) acc = fmaf(emb[k], W[k * DC_ + e], acc);
  ge[w][e] = sigm(acc) * emb[e];
  __syncthreads();
  float acc2 = com_b[e];
  #pragma unroll 8
  for (int k = 0; k < DC_; ++k) acc2 = fmaf(ge[w][k], com_W[k * DW_ + e], acc2);
  Vtab[((size_t)v * L_ + w) * DW_ + e] = tanhf(acc2);
}

// ------------------------------------------------------------------
// Kernel 2: distributed scan, S=4 x R=2, blk = s*64+g, 512 threads.
// R3 structure (verified, floor 2098us).
// THIS ROUND (R4): XCD-local mailbox fast path. Agent-scope atomics on
// gfx950 are coherent at the Infinity Cache (per-XCD L2s aren't
// cross-coherent), so every publish/poll paid LLC latency AND all
// spinning blocks hammered the single LLC. Partners blk+{0,64,128,192}
// are same-XCD under round-robin dispatch (blk%8 preserved). One-time
// handshake: each block publishes s_getreg(HW_REG_XCC_ID) agent-scope;
// if all 4 match (and <8) -> plain stores + sc0-load polls (XCD L2,
// ~200cy, 8x distributed). Mismatch -> agent path (=R3). Every 16th
// poll round uses agent loads regardless, so a wrong fast-path verdict
// degrades to slow polling, never a hang. FP math untouched.
// ------------------------------------------------------------------
__global__ __launch_bounds__(512, 2) void seq_kernel(
    const int* __restrict__ chars, const float* __restrict__ Vtab,
    const float* __restrict__ Kmat, const float* __restrict__ lstm_bias,
    const float* __restrict__ pred_W, const float* __restrict__ pred_b,
    const float* __restrict__ score_U, const float* __restrict__ bos,
    float* __restrict__ out, u64w* __restrict__ nh_mb, u64w* __restrict__ pp_mb,
    u64w* __restrict__ xcc_mb)
{
  const int blk = blockIdx.x;
  const int s = blk >> 6;      // 0..3 column-split (partners stride 64 -> same XCD %8)
  const int g = blk & 63;      // group id
  const int tid = threadIdx.x;
  const int lane = tid & 63;
  const int wv = tid >> 6;
  const int c = tid & 255;     // my z-column (local)
  const int koff = (tid < 256) ? 0 : 192;
  const int colg = (c >> 6) * H_ + s * 64 + (c & 63);  // global z-column
  const int row0 = g * R_;

  // ---- handshake publish (earliest possible; poll happens after bos) ----
  if (tid == 0) {
    // HW_REG_XCC_ID = id 20, offset 0, width 32 -> imm 20 | (31<<11)
    unsigned xcc = __builtin_amdgcn_s_getreg(20 | (31 << 11)) & 0xFFu;
    pub64u(&xcc_mb[(size_t)s * G_ + g], xcc, XCC_MAGIC);
  }

  // ---- weight registers: K[koff+i][colg], i = 0..191 ----
  float wreg[192];
  #pragma unroll
  for (int i = 0; i < 192; ++i)
    wreg[i] = Kmat[(size_t)(koff + i) * Z4_ + colg];

  __shared__ float ringVt[R_][4][512];      // 16 KB
  __shared__ float pring[4][R_][DW_];       // 4 KB
  __shared__ float zring[4][R_][256];       // 8 KB (also bos z scratch)
  __shared__ float cring[4][R_][64];        // 2 KB
  __shared__ float zhA[R_][256];            // 2 KB (type-A zh partials)
  __shared__ float zhB[R_][256];            // 2 KB (type-B zh partials)
  __shared__ float zxL[R_][256];            // 2 KB
  __shared__ float predWL[64][128];         // 32 KB (my pred_W slice)
  __shared__ float h1tmp[H_];               // 1 KB (init only)
  __shared__ int   charsL[R_][T_];          // 2 KB
  __shared__ float biasC[256], UL[128], pbL[128];
  __shared__ float scL[R_][L_];
  __shared__ int   fastL2s;

  // ---- one-time loads ----
  if (tid < 256) biasC[tid] = lstm_bias[(tid >> 6) * H_ + s * 64 + (tid & 63)];
  if (tid < 128) { UL[tid] = score_U[tid]; pbL[tid] = pred_b[tid]; }
  for (int i = tid; i < 64 * 128; i += 512)
    predWL[i >> 7][i & 127] = pred_W[(size_t)(s * 64 + (i >> 7)) * DW_ + (i & 127)];
  for (int i = tid; i < R_ * T_; i += 512)
    charsL[i >> 8][i & 255] = chars[(row0 + (i >> 8)) * T_ + (i & 255)];
  for (int i = tid; i < R_ * 4 * 512; i += 512) ((float*)ringVt)[i] = 0.0f;
  __syncthreads();

  // ---- bos step (x=bos, c0=h0=0): h1/c1, pred0, zh1 ----
  {
    float* zb = &zring[0][0][0];   // 1024-float scratch (slots 0-1)
    for (int c2 = tid; c2 < Z4_; c2 += 512) {
      float a = lstm_bias[c2];
      #pragma unroll 8
      for (int k = 0; k < DC_; ++k) a = fmaf(bos[k], Kmat[(size_t)k * Z4_ + c2], a);
      zb[c2] = a;
    }
    __syncthreads();
    if (tid < H_) {
      float zi = zb[tid], zj = zb[H_ + tid], zo = zb[3 * H_ + tid];
      float nc = sigm(zi) * tanhf(zj);
      float nh = tanhf(nc) * sigm(zo);
      h1tmp[tid] = nh;
      int hl = tid - s * 64;
      if (hl >= 0 && hl < 64) {
        #pragma unroll
        for (int q = 0; q < 4; ++q)
          #pragma unroll
          for (int r = 0; r < R_; ++r) cring[q][r][hl] = nc;
      }
    }
    __syncthreads();
    { // pred0 partials into zhA scratch (512 floats)
      int kq = tid >> 7, e = tid & 127;
      float a = 0.0f;
      #pragma unroll 8
      for (int k = kq * 64; k < kq * 64 + 64; ++k)
        a = fmaf(h1tmp[k], pred_W[(size_t)k * DW_ + e], a);
      ((float*)zhA)[kq * 128 + e] = a;
    }
    __syncthreads();
    if (tid < 128) {
      const float* pa = (const float*)zhA;
      float p = tanhf(pbL[tid] + pa[tid] + pa[128 + tid] + pa[256 + tid] + pa[384 + tid]);
      #pragma unroll
      for (int q = 0; q < 4; ++q)
        #pragma unroll
        for (int r = 0; r < R_; ++r) pring[q][r][tid] = p;
    }
    __syncthreads();   // pred0 partials consumed; zb consumed (h1 extracted)
    { // zh1 = Kh @ h1 via register weights (h1 same for both rows)
      float a = 0.0f;
      if (tid < 256) {
        #pragma unroll
        for (int k = 0; k < 64; ++k) a = fmaf(h1tmp[k], wreg[128 + k], a);
      } else {
        #pragma unroll
        for (int k = 0; k < 192; ++k) a = fmaf(h1tmp[64 + k], wreg[k], a);
      }
      __syncthreads();
      if (tid < 256) zhA[0][c] = a; else zhB[0][c] = a;
    }
    __syncthreads();
    if (tid < 256) {
      float z1 = zhA[0][tid] + zhB[0][tid];
      #pragma unroll
      for (int q = 0; q < 4; ++q)
        #pragma unroll
        for (int r = 0; r < R_; ++r) zring[q][r][tid] = z1;
    }
  }

  // ---- handshake poll: all 4 partners on one XCD? ----
  if (tid == 0) {
    unsigned v0 = 0xFFFFu, okf = 1;
    #pragma unroll
    for (int sp = 0; sp < S_; ++sp) {
      u64w w;
      do { w = ld64(&xcc_mb[(size_t)sp * G_ + g]); } while ((unsigned)w != XCC_MAGIC);
      unsigned xv = (unsigned)(w >> 32);
      if (sp == 0) v0 = xv;
      okf &= (xv == v0);
    }
    okf &= (v0 < 8u);
    fastL2s = (int)okf;
  }
  __syncthreads();
  const bool fastL2 = (fastL2s != 0);

  // ---- scan ----
  for (int t = 0; t < T_; ++t) {
    const int slot = t & 3;
    const int parR = (t - 1) & 1;
    const int parW = t & 1;
    const unsigned stR = (unsigned)t;
    const unsigned stW = (unsigned)(t + 1);

    // ===== S0: specialized waves =====
    // Vtab gather first (waves 2-3) so the global loads are in flight
    // while the same waves then poll the nh mailbox.
    if ((wv >> 1) == 1) {
      int i2 = tid & 127;
      #pragma unroll
      for (int r = 0; r < R_; ++r) {
        const float* vp = Vtab + (size_t)charsL[r][t] * 512;
        #pragma unroll
        for (int q = 0; q < 4; ++q) ringVt[r][slot][q * 128 + i2] = vp[q * 128 + i2];
      }
    }

    if (t > 0) {
      const u64w* nb = nh_mb + ((size_t)parR * G_ + g) * (R_ * H_);
      if (wv < 2) {
        // poll nh first (2 words) -> zh off the pp-wait
        u64w nw0, nw1;
        if (fastL2) {
          int rd = 0;
          for (;;) {
            if ((rd++ & 15) == 15) {
              nw0 = ld64(nb + lane); nw1 = ld64(nb + H_ + lane);
            } else {
              nw0 = ld64_l2_issue(nb + lane);
              nw1 = ld64_l2_issue(nb + H_ + lane);
              vm_wait0();
            }
            int ok = ((unsigned)nw0 == stR) & ((unsigned)nw1 == stR);
            if (__all(ok)) break;
            __builtin_amdgcn_s_sleep(1);
          }
        } else {
          for (;;) {
            nw0 = ld64(nb + lane);
            nw1 = ld64(nb + H_ + lane);
            int ok = ((unsigned)nw0 == stR) & ((unsigned)nw1 == stR);
            if (__all(ok)) break;
            __builtin_amdgcn_s_sleep(1);
          }
        }
        // zh(t-1) partial over h[0:64] via register weights (needs only nh)
        float nv0 = hi32(nw0), nv1 = hi32(nw1);
        float z0 = 0.0f, z1 = 0.0f;
        #pragma unroll
        for (int k = 0; k < 64; ++k) {
          float w = wreg[128 + k];
          z0 = fmaf(bcast(nv0, k), w, z0);
          z1 = fmaf(bcast(nv1, k), w, z1);
        }
        zhA[0][c] = z0; zhA[1][c] = z1;
        // pp poll (partners publish pp ~400cy after nh; usually arrived)
        const u64w* ppb = pp_mb + ((size_t)parR * G_ + g) * (S_ * R_ * 128) + wv * 128;
        u64w pw0[S_], pw1[S_];
        if (fastL2) {
          int rd = 0;
          for (;;) {
            if ((rd++ & 15) == 15) {
              #pragma unroll
              for (int sp = 0; sp < S_; ++sp) {
                pw0[sp] = ld64(ppb + (size_t)sp * (R_ * 128) + lane);
                pw1[sp] = ld64(ppb + (size_t)sp * (R_ * 128) + lane + 64);
              }
            } else {
              #pragma unroll
              for (int sp = 0; sp < S_; ++sp) {
                pw0[sp] = ld64_l2_issue(ppb + (size_t)sp * (R_ * 128) + lane);
                pw1[sp] = ld64_l2_issue(ppb + (size_t)sp * (R_ * 128) + lane + 64);
              }
              vm_wait0();
            }
            int ok = 1;
            #pragma unroll
            for (int sp = 0; sp < S_; ++sp)
              ok &= ((unsigned)pw0[sp] == stR) & ((unsigned)pw1[sp] == stR);
            if (__all(ok)) break;
            __builtin_amdgcn_s_sleep(1);
          }
        } else {
          for (;;) {
            #pragma unroll
            for (int sp = 0; sp < S_; ++sp) {
              pw0[sp] = ld64(ppb + (size_t)sp * (R_ * 128) + lane);
              pw1[sp] = ld64(ppb + (size_t)sp * (R_ * 128) + lane + 64);
            }
            int ok = 1;
            #pragma unroll
            for (int sp = 0; sp < S_; ++sp)
              ok &= ((unsigned)pw0[sp] == stR) & ((unsigned)pw1[sp] == stR);
            if (__all(ok)) break;
            __builtin_amdgcn_s_sleep(1);
          }
        }
        // pred(t-1) for row r=wv (sum order = sp 0..3, matches prior rounds)
        float a0 = pbL[lane], a1 = pbL[lane + 64];
        #pragma unroll
        for (int sp = 0; sp < S_; ++sp) {
          a0 += hi32(pw0[sp]);
          a1 += hi32(pw1[sp]);
        }
        int ps = (t - 1) & 3;
        pring[ps][wv][lane] = tanhf(a0);
        pring[ps][wv][lane + 64] = tanhf(a1);
      } else if (wv < 4) {
        // branch-free poll: 2 nh words (gather loads already issued)
        u64w nw0, nw1;
        if (fastL2) {
          int rd = 0;
          for (;;) {
            if ((rd++ & 15) == 15) {
              nw0 = ld64(nb + lane); nw1 = ld64(nb + H_ + lane);
            } else {
              nw0 = ld64_l2_issue(nb + lane);
              nw1 = ld64_l2_issue(nb + H_ + lane);
              vm_wait0();
            }
            int ok = ((unsigned)nw0 == stR) & ((unsigned)nw1 == stR);
            if (__all(ok)) break;
            __builtin_amdgcn_s_sleep(1);
          }
        } else {
          for (;;) {
            nw0 = ld64(nb + lane);
            nw1 = ld64(nb + H_ + lane);
            int ok = ((unsigned)nw0 == stR) & ((unsigned)nw1 == stR);
            if (__all(ok)) break;
            __builtin_amdgcn_s_sleep(1);
          }
        }
        float nv0 = hi32(nw0), nv1 = hi32(nw1);
        float z0 = 0.0f, z1 = 0.0f;
        #pragma unroll
        for (int k = 0; k < 64; ++k) {
          float w = wreg[128 + k];
          z0 = fmaf(bcast(nv0, k), w, z0);
          z1 = fmaf(bcast(nv1, k), w, z1);
        }
        zhA[0][c] = z0; zhA[1][c] = z1;
      } else {
        // branch-free poll: 6 nh words per round (h[64:256], rows 0-1)
        u64w nw[2][3];
        if (fastL2) {
          int rd = 0;
          for (;;) {
            if ((rd++ & 15) == 15) {
              #pragma unroll
              for (int r = 0; r < 2; ++r)
                #pragma unroll
                for (int j = 0; j < 3; ++j)
                  nw[r][j] = ld64(nb + (size_t)r * H_ + 64 + j * 64 + lane);
            } else {
              #pragma unroll
              for (int r = 0; r < 2; ++r)
                #pragma unroll
                for (int j = 0; j < 3; ++j)
                  nw[r][j] = ld64_l2_issue(nb + (size_t)r * H_ + 64 + j * 64 + lane);
              vm_wait0();
            }
            int ok = 1;
            #pragma unroll
            for (int r = 0; r < 2; ++r)
              #pragma unroll
              for (int j = 0; j < 3; ++j)
                ok &= ((unsigned)nw[r][j] == stR);
            if (__all(ok)) break;
            __builtin_amdgcn_s_sleep(1);
          }
        } else {
          for (;;) {
            #pragma unroll
            for (int r = 0; r < 2; ++r)
              #pragma unroll
              for (int j = 0; j < 3; ++j)
                nw[r][j] = ld64(nb + (size_t)r * H_ + 64 + j * 64 + lane);
            int ok = 1;
            #pragma unroll
            for (int r = 0; r < 2; ++r)
              #pragma unroll
              for (int j = 0; j < 3; ++j)
                ok &= ((unsigned)nw[r][j] == stR);
            if (__all(ok)) break;
            __builtin_amdgcn_s_sleep(1);
          }
        }
        float a0 = 0.0f, a1 = 0.0f;
        #pragma unroll
        for (int j = 0; j < 3; ++j) {
          float nv0 = hi32(nw[0][j]), nv1 = hi32(nw[1][j]);
          #pragma unroll
          for (int k = 0; k < 64; ++k) {
            float w = wreg[j * 64 + k];
            a0 = fmaf(bcast(nv0, k), w, a0);
            a1 = fmaf(bcast(nv1, k), w, a1);
          }
        }
        zhB[0][c] = a0; zhB[1][c] = a1;
      }
    }
    __syncthreads();                                   // B1

    // ===== S1: zring(t-1) reduce + scores =====
    if (t > 0) {
      int r = tid >> 8, cc = tid & 255;
      zring[(t - 1) & 3][r][cc] = zhA[r][cc] + zhB[r][cc];
    }
    {
      int r = wv >> 2, w = wv & 3;
      int ps = (t - 1 - w) & 3;
      float il = invlen(w);
      float acc = 0.0f;
      #pragma unroll
      for (int hf = 0; hf < 2; ++hf) {
        int e = lane + hf * 64;
        float sa = 0.0f;
        #pragma unroll
        for (int c2 = 0; c2 < L_; ++c2)
          if (c2 <= w) sa += ringVt[r][(t - c2) & 3][w * 128 + e];
        acc = fmaf(pring[ps][r][e] + UL[e], sa * il, acc);
      }
      #pragma unroll
      for (int off = 32; off; off >>= 1) acc += __shfl_down(acc, off);
      if (lane == 0) scL[r][w] = (w <= t) ? acc : NEGF;
    }
    __syncthreads();                                   // B2

    // ===== S2: vtsel (lanes) + zx via register Kx + outputs =====
    if (tid < 256) {
      float vt0[2], vt1[2];
      #pragma unroll
      for (int r = 0; r < 2; ++r) {
        int bw = amax4(scL[r]);
        float il = invlen(bw);
        float v0 = 0.f, v1 = 0.f;
        #pragma unroll
        for (int c2 = 0; c2 < L_; ++c2)
          if (c2 <= bw) {
            v0 += ringVt[r][(t - c2) & 3][bw * 128 + lane];
            v1 += ringVt[r][(t - c2) & 3][bw * 128 + 64 + lane];
          }
        vt0[r] = v0 * il; vt1[r] = v1 * il;
      }
      float a0 = 0.f, a1 = 0.f;
      #pragma unroll
      for (int k = 0; k < 64; ++k) {
        float w0 = wreg[k], w1 = wreg[64 + k];
        a0 = fmaf(bcast(vt0[0], k), w0, a0);
        a1 = fmaf(bcast(vt0[1], k), w0, a1);
        a0 = fmaf(bcast(vt1[0], k), w1, a0);
        a1 = fmaf(bcast(vt1[1], k), w1, a1);
      }
      zxL[0][c] = a0; zxL[1][c] = a1;
      if (s == 0 && tid < R_) {
        int bw = amax4(scL[tid]);
        out[(row0 + tid) * T_ + t] = scL[tid][bw];
        out[B_ * T_ + (row0 + tid) * T_ + t] = (float)(bw + 1);
      }
    }
    __syncthreads();                                   // B3

    // ===== S3 (waves 0-1): gates -> publish nh; in-wave pp -> publish =====
    // Waves 2-7 race into next step's S0 (stamps self-synchronize).
    if (tid < 128) {
      int r = wv, hl = lane;
      int bw = amax4(scL[r]);
      int zs = (t - 1 - bw) & 3;
      float zg[4];
      #pragma unroll
      for (int gi = 0; gi < 4; ++gi) {
        int cc = gi * 64 + hl;
        zg[gi] = biasC[cc] + zring[zs][r][cc] + zxL[r][cc];
      }
      float cp = cring[zs][r][hl];
      float nc = cp * sigm(zg[2]) + sigm(zg[0]) * tanhf(zg[1]);
      float nh = tanhf(nc) * sigm(zg[3]);
      u64w* pnh = &nh_mb[((size_t)parW * G_ + g) * (R_ * H_) + (size_t)r * H_ + s * 64 + hl];
      if (fastL2) *pnh = packw(nh, stW);
      else        __hip_atomic_store(pnh, packw(nh, stW), __ATOMIC_RELAXED, __HIP_MEMORY_SCOPE_AGENT);
      cring[slot][r][hl] = nc;
      // pp partial over my 64 h-rows, fully in-wave (shfl broadcast + LDS predW)
      float p0 = 0.f, p1 = 0.f;
      #pragma unroll
      for (int kk = 0; kk < 64; ++kk) {
        float nb2 = __shfl(nh, kk, 64);
        p0 = fmaf(nb2, predWL[kk][lane], p0);
        p1 = fmaf(nb2, predWL[kk][lane + 64], p1);
      }
      u64w* pb = pp_mb + ((size_t)parW * G_ + g) * (S_ * R_ * 128)
               + (size_t)s * (R_ * 128) + (size_t)r * 128;
      if (fastL2) {
        pb[lane] = packw(p0, stW);
        pb[lane + 64] = packw(p1, stW);
      } else {
        pub64(pb + lane, p0, stW);
        pub64(pb + lane + 64, p1, stW);
      }
    }
    // no barrier: next iteration's B1 re-converges
  }
}

extern "C" void kernel_launch(void* const* d_in, const int* in_sizes, int n_in,
                              void* d_out, int out_size, void* d_ws, size_t ws_size,
                              hipStream_t stream) {
  const int*   chars     = (const int*)d_in[0];
  const float* char_emb  = (const float*)d_in[1];
  const float* reset_W   = (const float*)d_in[2];
  const float* reset_b   = (const float*)d_in[3];
  const float* com_W     = (const float*)d_in[4];
  const float* com_b     = (const float*)d_in[5];
  const float* lstm_k    = (const float*)d_in[6];
  const float* lstm_bias = (const float*)d_in[7];
  const float* pred_W    = (const float*)d_in[8];
  const float* pred_b    = (const float*)d_in[9];
  const float* score_U   = (const float*)d_in[10];
  const float* bos       = (const float*)d_in[11];

  char* ws = (char*)d_ws;
  float* Vtab = (float*)(ws + WS_VTAB);
  u64w* nh_mb = (u64w*)(ws + WS_NH);
  u64w* pp_mb = (u64w*)(ws + WS_PP);
  u64w* xcc_mb = (u64w*)(ws + WS_XCC);
  // No flags, no memset: the 0xAA poison word never matches a stamp in [1,256]
  // nor the XCC_MAGIC handshake stamp.

  vtab_kernel<<<V_, 512, 0, stream>>>(char_emb, reset_W, reset_b, com_W, com_b, Vtab);
  seq_kernel<<<256, 512, 0, stream>>>(chars, Vtab, lstm_k, lstm_bias, pred_W,
                                      pred_b, score_U, bos, (float*)d_out,
                                      nh_mb, pp_mb, xcc_mb);
}

// Round 6
// 2450.288 us; speedup vs baseline: 1.1839x; 1.1839x over previous
//
#include <hip/hip_runtime.h>

#define B_ 128
#define T_ 256
#define L_ 4
#define DC_ 128
#define DW_ 128
#define H_ 256
#define V_ 6000
#define Z4_ 1024   // 4*H
#define S_ 4       // blocks per group (z-column split)
#define R_ 2       // batch rows per group
#define G_ 64      // groups = B/R
#define NEGF -1e30f

// d_ws layout (bytes). Stamps live inside data words — no flags, no memset.
#define WS_VTAB  4096                          // V*L*DW f32 = 12,288,000
#define WS_NH    (WS_VTAB + V_*L_*DW_*4)       // u64 [2][G][R][H]      = 512 KB
#define WS_PP    (WS_NH + (size_t)2*G_*R_*H_*8)// u64 [2][G][S][R][128] = 1 MB

typedef unsigned long long u64w;

__device__ __forceinline__ float sigm(float x) { return 1.0f / (1.0f + expf(-x)); }
__device__ __forceinline__ void pub64(u64w* p, float v, unsigned stamp) {
  u64w w = ((u64w)__float_as_uint(v) << 32) | (u64w)stamp;
  __hip_atomic_store(p, w, __ATOMIC_RELAXED, __HIP_MEMORY_SCOPE_AGENT);
}
__device__ __forceinline__ u64w ld64(const u64w* p) {
  return __hip_atomic_load(p, __ATOMIC_RELAXED, __HIP_MEMORY_SCOPE_AGENT);
}
__device__ __forceinline__ float hi32(u64w w) {
  return __uint_as_float((unsigned)(w >> 32));
}
// wave-broadcast from lane l via v_readlane (result lands in an SGPR — no VGPR cost)
__device__ __forceinline__ float bcast(float v, int l) {
  return __int_as_float(__builtin_amdgcn_readlane(__float_as_int(v), l));
}
__device__ __forceinline__ int amax4(const float* sc) {   // first-max-wins (jnp.argmax)
  float bs = sc[0]; int bw = 0;
  if (sc[1] > bs) { bs = sc[1]; bw = 1; }
  if (sc[2] > bs) { bs = sc[2]; bw = 2; }
  if (sc[3] > bs) { bs = sc[3]; bw = 3; }
  return bw;
}
__device__ __forceinline__ float invlen(int w) {
  return (w == 0) ? 1.0f : (w == 1) ? 0.5f : (w == 2) ? (1.0f / 3.0f) : 0.25f;
}

// ------------------------------------------------------------------
// Kernel 1: vocab composition table (unchanged — verified).
// ------------------------------------------------------------------
__global__ __launch_bounds__(512) void vtab_kernel(
    const float* __restrict__ char_emb, const float* __restrict__ reset_W,
    const float* __restrict__ reset_b, const float* __restrict__ com_W,
    const float* __restrict__ com_b, float* __restrict__ Vtab)
{
  const int v = blockIdx.x;
  const int tid = threadIdx.x;
  const int w = tid >> 7;
  const int e = tid & 127;
  __shared__ float emb[DC_];
  __shared__ float ge[L_][DC_];
  if (tid < DC_) emb[tid] = char_emb[v * DC_ + tid];
  __syncthreads();
  float acc = reset_b[w * DC_ + e];
  const float* W = reset_W + (size_t)w * DC_ * DC_;
  #pragma unroll 8
  for (int k = 0; k < DC_; ++k) acc = fmaf(emb[k], W[k * DC_ + e], acc);
  ge[w][e] = sigm(acc) * emb[e];
  __syncthreads();
  float acc2 = com_b[e];
  #pragma unroll 8
  for (int k = 0; k < DC_; ++k) acc2 = fmaf(ge[w][k], com_W[k * DW_ + e], acc2);
  Vtab[((size_t)v * L_ + w) * DW_ + e] = tanhf(acc2);
}

// ------------------------------------------------------------------
// Kernel 2: distributed scan, S=4 x R=2, blk = s*64+g, 512 threads.
// R3 verified base (floor 2098us). R4/R5 L2-mailbox fast path
// ABANDONED (R4: visibility pathology, +700us; R5: hang). Mailboxes
// stay agent-scope __hip_atomic only.
// THIS ROUND (R6): R2's zh-deferral done safely. zring is consumed
// only in S3, so the upper waves' 768-instr zh matvec need not gate
// B1. Cross-barrier state goes through LDS (exact bits), never
// registers (R2's scratch-spill lesson):
//  - wave 4 alone polls the 6 upper nh words, stores payloads to
//    nhL[6][64]; waves 5-7 skip S0 (B1 transfers the detection).
//  - waves 4-7: S1 window = zh slices j=0,1 (reading nhL), partial
//    parked in zhB (LDS); S2 window = slice j=2 + zring = zhA + zh.
//  - scores move to waves 0-3, two (r,w)-pairs each (R2-verified).
//  - setprio(1) around S3 gates+publish.
// All accumulation orders bit-identical to R3.
// ------------------------------------------------------------------
__global__ __launch_bounds__(512, 2) void seq_kernel(
    const int* __restrict__ chars, const float* __restrict__ Vtab,
    const float* __restrict__ Kmat, const float* __restrict__ lstm_bias,
    const float* __restrict__ pred_W, const float* __restrict__ pred_b,
    const float* __restrict__ score_U, const float* __restrict__ bos,
    float* __restrict__ out, u64w* __restrict__ nh_mb, u64w* __restrict__ pp_mb)
{
  const int blk = blockIdx.x;
  const int s = blk >> 6;      // 0..3 column-split (partners stride 64 -> same XCD %8)
  const int g = blk & 63;      // group id
  const int tid = threadIdx.x;
  const int lane = tid & 63;
  const int wv = tid >> 6;
  const int c = tid & 255;     // my z-column (local)
  const int koff = (tid < 256) ? 0 : 192;
  const int colg = (c >> 6) * H_ + s * 64 + (c & 63);  // global z-column
  const int row0 = g * R_;

  // ---- weight registers: K[koff+i][colg], i = 0..191 ----
  float wreg[192];
  #pragma unroll
  for (int i = 0; i < 192; ++i)
    wreg[i] = Kmat[(size_t)(koff + i) * Z4_ + colg];

  __shared__ float ringVt[R_][4][512];      // 16 KB
  __shared__ float pring[4][R_][DW_];       // 4 KB
  __shared__ float zring[4][R_][256];       // 8 KB (also bos z scratch)
  __shared__ float cring[4][R_][64];        // 2 KB
  __shared__ float zhA[R_][256];            // 2 KB (lower-half zh partials)
  __shared__ float zhB[R_][256];            // 2 KB (upper zh partial carrier)
  __shared__ float zxL[R_][256];            // 2 KB
  __shared__ float nhL[6][64];              // 1.5 KB (upper nh payloads, w4-written)
  __shared__ float predWL[64][128];         // 32 KB (my pred_W slice)
  __shared__ float h1tmp[H_];               // 1 KB (init only)
  __shared__ int   charsL[R_][T_];          // 2 KB
  __shared__ float biasC[256], UL[128], pbL[128];
  __shared__ float scL[R_][L_];

  // ---- one-time loads ----
  if (tid < 256) biasC[tid] = lstm_bias[(tid >> 6) * H_ + s * 64 + (tid & 63)];
  if (tid < 128) { UL[tid] = score_U[tid]; pbL[tid] = pred_b[tid]; }
  for (int i = tid; i < 64 * 128; i += 512)
    predWL[i >> 7][i & 127] = pred_W[(size_t)(s * 64 + (i >> 7)) * DW_ + (i & 127)];
  for (int i = tid; i < R_ * T_; i += 512)
    charsL[i >> 8][i & 255] = chars[(row0 + (i >> 8)) * T_ + (i & 255)];
  for (int i = tid; i < R_ * 4 * 512; i += 512) ((float*)ringVt)[i] = 0.0f;
  __syncthreads();

  // ---- bos step (x=bos, c0=h0=0): h1/c1, pred0, zh1 ----
  {
    float* zb = &zring[0][0][0];   // 1024-float scratch (slots 0-1)
    for (int c2 = tid; c2 < Z4_; c2 += 512) {
      float a = lstm_bias[c2];
      #pragma unroll 8
      for (int k = 0; k < DC_; ++k) a = fmaf(bos[k], Kmat[(size_t)k * Z4_ + c2], a);
      zb[c2] = a;
    }
    __syncthreads();
    if (tid < H_) {
      float zi = zb[tid], zj = zb[H_ + tid], zo = zb[3 * H_ + tid];
      float nc = sigm(zi) * tanhf(zj);
      float nh = tanhf(nc) * sigm(zo);
      h1tmp[tid] = nh;
      int hl = tid - s * 64;
      if (hl >= 0 && hl < 64) {
        #pragma unroll
        for (int q = 0; q < 4; ++q)
          #pragma unroll
          for (int r = 0; r < R_; ++r) cring[q][r][hl] = nc;
      }
    }
    __syncthreads();
    { // pred0 partials into zhA scratch (512 floats)
      int kq = tid >> 7, e = tid & 127;
      float a = 0.0f;
      #pragma unroll 8
      for (int k = kq * 64; k < kq * 64 + 64; ++k)
        a = fmaf(h1tmp[k], pred_W[(size_t)k * DW_ + e], a);
      ((float*)zhA)[kq * 128 + e] = a;
    }
    __syncthreads();
    if (tid < 128) {
      const float* pa = (const float*)zhA;
      float p = tanhf(pbL[tid] + pa[tid] + pa[128 + tid] + pa[256 + tid] + pa[384 + tid]);
      #pragma unroll
      for (int q = 0; q < 4; ++q)
        #pragma unroll
        for (int r = 0; r < R_; ++r) pring[q][r][tid] = p;
    }
    __syncthreads();   // pred0 partials consumed; zb consumed (h1 extracted)
    { // zh1 = Kh @ h1 via register weights (h1 same for both rows)
      float a = 0.0f;
      if (tid < 256) {
        #pragma unroll
        for (int k = 0; k < 64; ++k) a = fmaf(h1tmp[k], wreg[128 + k], a);
      } else {
        #pragma unroll
        for (int k = 0; k < 192; ++k) a = fmaf(h1tmp[64 + k], wreg[k], a);
      }
      __syncthreads();
      if (tid < 256) zhA[0][c] = a; else zhB[0][c] = a;
    }
    __syncthreads();
    if (tid < 256) {
      float z1 = zhA[0][tid] + zhB[0][tid];
      #pragma unroll
      for (int q = 0; q < 4; ++q)
        #pragma unroll
        for (int r = 0; r < R_; ++r) zring[q][r][tid] = z1;
    }
    __syncthreads();
  }

  // ---- scan ----
  for (int t = 0; t < T_; ++t) {
    const int slot = t & 3;
    const int parR = (t - 1) & 1;
    const int parW = t & 1;
    const unsigned stR = (unsigned)t;
    const unsigned stW = (unsigned)(t + 1);

    // ===== S0: specialized waves =====
    // Vtab gather first (waves 2-3) so the global loads are in flight
    // while the same waves then poll the nh mailbox.
    if ((wv >> 1) == 1) {
      int i2 = tid & 127;
      #pragma unroll
      for (int r = 0; r < R_; ++r) {
        const float* vp = Vtab + (size_t)charsL[r][t] * 512;
        #pragma unroll
        for (int q = 0; q < 4; ++q) ringVt[r][slot][q * 128 + i2] = vp[q * 128 + i2];
      }
    }

    if (t > 0) {
      const u64w* nb = nh_mb + ((size_t)parR * G_ + g) * (R_ * H_);
      if (wv < 2) {
        // poll nh first (2 words) -> zh off the pp-wait
        u64w nw0, nw1;
        for (;;) {
          nw0 = ld64(nb + lane);
          nw1 = ld64(nb + H_ + lane);
          int ok = ((unsigned)nw0 == stR) & ((unsigned)nw1 == stR);
          if (__all(ok)) break;
          __builtin_amdgcn_s_sleep(1);
        }
        // zh(t-1) partial over h[0:64] via register weights (needs only nh)
        float nv0 = hi32(nw0), nv1 = hi32(nw1);
        float z0 = 0.0f, z1 = 0.0f;
        #pragma unroll
        for (int k = 0; k < 64; ++k) {
          float w = wreg[128 + k];
          z0 = fmaf(bcast(nv0, k), w, z0);
          z1 = fmaf(bcast(nv1, k), w, z1);
        }
        zhA[0][c] = z0; zhA[1][c] = z1;
        // pp poll (partners publish pp ~400cy after nh; usually arrived)
        const u64w* ppb = pp_mb + ((size_t)parR * G_ + g) * (S_ * R_ * 128) + wv * 128;
        u64w pw0[S_], pw1[S_];
        for (;;) {
          #pragma unroll
          for (int sp = 0; sp < S_; ++sp) {
            pw0[sp] = ld64(ppb + (size_t)sp * (R_ * 128) + lane);
            pw1[sp] = ld64(ppb + (size_t)sp * (R_ * 128) + lane + 64);
          }
          int ok = 1;
          #pragma unroll
          for (int sp = 0; sp < S_; ++sp)
            ok &= ((unsigned)pw0[sp] == stR) & ((unsigned)pw1[sp] == stR);
          if (__all(ok)) break;
          __builtin_amdgcn_s_sleep(1);
        }
        // pred(t-1) for row r=wv (sum order = sp 0..3, matches prior rounds)
        float a0 = pbL[lane], a1 = pbL[lane + 64];
        #pragma unroll
        for (int sp = 0; sp < S_; ++sp) {
          a0 += hi32(pw0[sp]);
          a1 += hi32(pw1[sp]);
        }
        int ps = (t - 1) & 3;
        pring[ps][wv][lane] = tanhf(a0);
        pring[ps][wv][lane + 64] = tanhf(a1);
      } else if (wv < 4) {
        // branch-free poll: 2 nh words (gather loads already issued)
        u64w nw0, nw1;
        for (;;) {
          nw0 = ld64(nb + lane);
          nw1 = ld64(nb + H_ + lane);
          int ok = ((unsigned)nw0 == stR) & ((unsigned)nw1 == stR);
          if (__all(ok)) break;
          __builtin_amdgcn_s_sleep(1);
        }
        float nv0 = hi32(nw0), nv1 = hi32(nw1);
        float z0 = 0.0f, z1 = 0.0f;
        #pragma unroll
        for (int k = 0; k < 64; ++k) {
          float w = wreg[128 + k];
          z0 = fmaf(bcast(nv0, k), w, z0);
          z1 = fmaf(bcast(nv1, k), w, z1);
        }
        zhA[0][c] = z0; zhA[1][c] = z1;
      } else if (wv == 4) {
        // sole poller for the 6 upper nh words; payloads -> nhL.
        // Waves 5-7 skip S0 — B1 transfers this detection to them.
        u64w nw[2][3];
        for (;;) {
          #pragma unroll
          for (int r = 0; r < 2; ++r)
            #pragma unroll
            for (int j = 0; j < 3; ++j)
              nw[r][j] = ld64(nb + (size_t)r * H_ + 64 + j * 64 + lane);
          int ok = 1;
          #pragma unroll
          for (int r = 0; r < 2; ++r)
            #pragma unroll
            for (int j = 0; j < 3; ++j)
              ok &= ((unsigned)nw[r][j] == stR);
          if (__all(ok)) break;
          __builtin_amdgcn_s_sleep(1);
        }
        #pragma unroll
        for (int r = 0; r < 2; ++r)
          #pragma unroll
          for (int j = 0; j < 3; ++j)
            nhL[r * 3 + j][lane] = hi32(nw[r][j]);
      }
    }
    __syncthreads();                                   // B1

    // ===== S1: scores (w0-3, two pairs each) | zh j=0,1 (w4-7) =====
    if (wv < 4) {
      #pragma unroll
      for (int r = 0; r < 2; ++r) {
        int w = wv;
        int ps = (t - 1 - w) & 3;
        float il = invlen(w);
        float acc = 0.0f;
        #pragma unroll
        for (int hf = 0; hf < 2; ++hf) {
          int e = lane + hf * 64;
          float sa = 0.0f;
          #pragma unroll
          for (int c2 = 0; c2 < L_; ++c2)
            if (c2 <= w) sa += ringVt[r][(t - c2) & 3][w * 128 + e];
          acc = fmaf(pring[ps][r][e] + UL[e], sa * il, acc);
        }
        #pragma unroll
        for (int off = 32; off; off >>= 1) acc += __shfl_down(acc, off);
        if (lane == 0) scL[r][w] = (w <= t) ? acc : NEGF;
      }
    } else if (t > 0) {
      // zh slices j=0,1 (k-chain order identical to R3); park partial in zhB
      float nv00 = nhL[0][lane], nv10 = nhL[3][lane];
      float nv01 = nhL[1][lane], nv11 = nhL[4][lane];
      float z0 = 0.0f, z1 = 0.0f;
      #pragma unroll
      for (int k = 0; k < 64; ++k) {
        float w = wreg[k];
        z0 = fmaf(bcast(nv00, k), w, z0);
        z1 = fmaf(bcast(nv10, k), w, z1);
      }
      #pragma unroll
      for (int k = 0; k < 64; ++k) {
        float w = wreg[64 + k];
        z0 = fmaf(bcast(nv01, k), w, z0);
        z1 = fmaf(bcast(nv11, k), w, z1);
      }
      zhB[0][c] = z0; zhB[1][c] = z1;
    }
    __syncthreads();                                   // B2

    // ===== S2: vtsel + zx + outputs (w0-3) | zh j=2 + zring (w4-7) =====
    if (tid < 256) {
      float vt0[2], vt1[2];
      #pragma unroll
      for (int r = 0; r < 2; ++r) {
        int bw = amax4(scL[r]);
        float il = invlen(bw);
        float v0 = 0.f, v1 = 0.f;
        #pragma unroll
        for (int c2 = 0; c2 < L_; ++c2)
          if (c2 <= bw) {
            v0 += ringVt[r][(t - c2) & 3][bw * 128 + lane];
            v1 += ringVt[r][(t - c2) & 3][bw * 128 + 64 + lane];
          }
        vt0[r] = v0 * il; vt1[r] = v1 * il;
      }
      float a0 = 0.f, a1 = 0.f;
      #pragma unroll
      for (int k = 0; k < 64; ++k) {
        float w0 = wreg[k], w1 = wreg[64 + k];
        a0 = fmaf(bcast(vt0[0], k), w0, a0);
        a1 = fmaf(bcast(vt0[1], k), w0, a1);
        a0 = fmaf(bcast(vt1[0], k), w1, a0);
        a1 = fmaf(bcast(vt1[1], k), w1, a1);
      }
      zxL[0][c] = a0; zxL[1][c] = a1;
      if (s == 0 && tid < R_) {
        int bw = amax4(scL[tid]);
        out[(row0 + tid) * T_ + t] = scL[tid][bw];
        out[B_ * T_ + (row0 + tid) * T_ + t] = (float)(bw + 1);
      }
    } else if (t > 0) {
      // zh slice j=2 (continue the parked accumulators) + zring reduce
      float nv02 = nhL[2][lane], nv12 = nhL[5][lane];
      float z0 = zhB[0][c], z1 = zhB[1][c];
      #pragma unroll
      for (int k = 0; k < 64; ++k) {
        float w = wreg[128 + k];
        z0 = fmaf(bcast(nv02, k), w, z0);
        z1 = fmaf(bcast(nv12, k), w, z1);
      }
      int zs2 = (t - 1) & 3;
      zring[zs2][0][c] = zhA[0][c] + z0;
      zring[zs2][1][c] = zhA[1][c] + z1;
    }
    __syncthreads();                                   // B3

    // ===== S3 (waves 0-1): gates -> publish nh; in-wave pp -> publish =====
    // Waves 2-7 race into next step's S0 (stamps self-synchronize).
    if (tid < 128) {
      __builtin_amdgcn_s_setprio(1);
      int r = wv, hl = lane;
      int bw = amax4(scL[r]);
      int zs = (t - 1 - bw) & 3;
      float zg[4];
      #pragma unroll
      for (int gi = 0; gi < 4; ++gi) {
        int cc = gi * 64 + hl;
        zg[gi] = biasC[cc] + zring[zs][r][cc] + zxL[r][cc];
      }
      float cp = cring[zs][r][hl];
      float nc = cp * sigm(zg[2]) + sigm(zg[0]) * tanhf(zg[1]);
      float nh = tanhf(nc) * sigm(zg[3]);
      pub64(&nh_mb[((size_t)parW * G_ + g) * (R_ * H_) + (size_t)r * H_ + s * 64 + hl],
            nh, stW);
      cring[slot][r][hl] = nc;
      // pp partial over my 64 h-rows, fully in-wave (shfl broadcast + LDS predW)
      float p0 = 0.f, p1 = 0.f;
      #pragma unroll
      for (int kk = 0; kk < 64; ++kk) {
        float nb2 = __shfl(nh, kk, 64);
        p0 = fmaf(nb2, predWL[kk][lane], p0);
        p1 = fmaf(nb2, predWL[kk][lane + 64], p1);
      }
      u64w* pb = pp_mb + ((size_t)parW * G_ + g) * (S_ * R_ * 128)
               + (size_t)s * (R_ * 128) + (size_t)r * 128;
      pub64(pb + lane, p0, stW);
      pub64(pb + lane + 64, p1, stW);
      __builtin_amdgcn_s_setprio(0);
    }
    // no barrier: next iteration's B1 re-converges
  }
}

extern "C" void kernel_launch(void* const* d_in, const int* in_sizes, int n_in,
                              void* d_out, int out_size, void* d_ws, size_t ws_size,
                              hipStream_t stream) {
  const int*   chars     = (const int*)d_in[0];
  const float* char_emb  = (const float*)d_in[1];
  const float* reset_W   = (const float*)d_in[2];
  const float* reset_b   = (const float*)d_in[3];
  const float* com_W     = (const float*)d_in[4];
  const float* com_b     = (const float*)d_in[5];
  const float* lstm_k    = (const float*)d_in[6];
  const float* lstm_bias = (const float*)d_in[7];
  const float* pred_W    = (const float*)d_in[8];
  const float* pred_b    = (const float*)d_in[9];
  const float* score_U   = (const float*)d_in[10];
  const float* bos       = (const float*)d_in[11];

  char* ws = (char*)d_ws;
  float* Vtab = (float*)(ws + WS_VTAB);
  u64w* nh_mb = (u64w*)(ws + WS_NH);
  u64w* pp_mb = (u64w*)(ws + WS_PP);
  // No flags, no memset: the 0xAA poison word never matches a stamp in [1,256].

  vtab_kernel<<<V_, 512, 0, stream>>>(char_emb, reset_W, reset_b, com_W, com_b, Vtab);
  seq_kernel<<<256, 512, 0, stream>>>(chars, Vtab, lstm_k, lstm_bias, pred_W,
                                      pred_b, score_U, bos, (float*)d_out,
                                      nh_mb, pp_mb);
}

// Round 7
// 2082.329 us; speedup vs baseline: 1.3931x; 1.1767x over previous
//
#include <hip/hip_runtime.h>

#define B_ 128
#define T_ 256
#define L_ 4
#define DC_ 128
#define DW_ 128
#define H_ 256
#define V_ 6000
#define Z4_ 1024   // 4*H
#define S_ 4       // blocks per group (z-column split)
#define R_ 2       // batch rows per group
#define G_ 64      // groups = B/R
#define NEGF -1e30f

// d_ws layout (bytes). Stamps live inside data words — no flags, no memset.
#define WS_VTAB  4096                          // V*L*DW f32 = 12,288,000
#define WS_NH    (WS_VTAB + V_*L_*DW_*4)       // u64 [2][G][R][H]      = 512 KB
#define WS_PP    (WS_NH + (size_t)2*G_*R_*H_*8)// u64 [2][G][S][R][128] = 1 MB

typedef unsigned long long u64w;

__device__ __forceinline__ float sigm(float x) { return 1.0f / (1.0f + expf(-x)); }
__device__ __forceinline__ void pub64(u64w* p, float v, unsigned stamp) {
  u64w w = ((u64w)__float_as_uint(v) << 32) | (u64w)stamp;
  __hip_atomic_store(p, w, __ATOMIC_RELAXED, __HIP_MEMORY_SCOPE_AGENT);
}
__device__ __forceinline__ u64w ld64(const u64w* p) {
  return __hip_atomic_load(p, __ATOMIC_RELAXED, __HIP_MEMORY_SCOPE_AGENT);
}
__device__ __forceinline__ float hi32(u64w w) {
  return __uint_as_float((unsigned)(w >> 32));
}
// wave-broadcast from lane l via v_readlane (result lands in an SGPR — no VGPR cost)
__device__ __forceinline__ float bcast(float v, int l) {
  return __int_as_float(__builtin_amdgcn_readlane(__float_as_int(v), l));
}
__device__ __forceinline__ int amax4(const float* sc) {   // first-max-wins (jnp.argmax)
  float bs = sc[0]; int bw = 0;
  if (sc[1] > bs) { bs = sc[1]; bw = 1; }
  if (sc[2] > bs) { bs = sc[2]; bw = 2; }
  if (sc[3] > bs) { bs = sc[3]; bw = 3; }
  return bw;
}
__device__ __forceinline__ float invlen(int w) {
  return (w == 0) ? 1.0f : (w == 1) ? 0.5f : (w == 2) ? (1.0f / 3.0f) : 0.25f;
}

// ------------------------------------------------------------------
// Kernel 1: vocab composition table (unchanged — verified).
// ------------------------------------------------------------------
__global__ __launch_bounds__(512) void vtab_kernel(
    const float* __restrict__ char_emb, const float* __restrict__ reset_W,
    const float* __restrict__ reset_b, const float* __restrict__ com_W,
    const float* __restrict__ com_b, float* __restrict__ Vtab)
{
  const int v = blockIdx.x;
  const int tid = threadIdx.x;
  const int w = tid >> 7;
  const int e = tid & 127;
  __shared__ float emb[DC_];
  __shared__ float ge[L_][DC_];
  if (tid < DC_) emb[tid] = char_emb[v * DC_ + tid];
  __syncthreads();
  float acc = reset_b[w * DC_ + e];
  const float* W = reset_W + (size_t)w * DC_ * DC_;
  #pragma unroll 8
  for (int k = 0; k < DC_; ++k) acc = fmaf(emb[k], W[k * DC_ + e], acc);
  ge[w][e] = sigm(acc) * emb[e];
  __syncthreads();
  float acc2 = com_b[e];
  #pragma unroll 8
  for (int k = 0; k < DC_; ++k) acc2 = fmaf(ge[w][k], com_W[k * DW_ + e], acc2);
  Vtab[((size_t)v * L_ + w) * DW_ + e] = tanhf(acc2);
}

// ------------------------------------------------------------------
// Kernel 2: distributed scan, S=4 x R=2, blk = s*64+g, 512 threads.
// R3 verified base (floor 2098us). R4/R5 L2-mailbox path abandoned;
// R2/R6 work-deferral regressed. Only mailbox-interaction cost
// reductions have ever won (R1 batch, R3 split).
// THIS ROUND (R7): LLC poll dedup via LDS relay. R3 has 4 waves
// polling the same 2 nh-lower words and 4 waves polling the same 6
// nh-upper words -> 48 lane-wide agent loads per round per block,
// x256 blocks = LLC contention (the suspected hidden 4x in step
// time). Now: w0 polls nh-lower and relays payload+stamp through
// LDS (workgroup acquire/release); w2-3 spin on LDS (zero LLC
// traffic). w4 polls nh-upper, relays; w5-7 spin on LDS. w1 keeps
// its own LLC poll (it polls pp anyway). Poll streams 48 -> 18.
// zh chains read the SAME bits (exact f32 via LDS) in the SAME
// order -> bit-identical outputs. S3: __shfl -> readlane (identical
// value), setprio(1) around gates+publish.
// ------------------------------------------------------------------
__global__ __launch_bounds__(512, 2) void seq_kernel(
    const int* __restrict__ chars, const float* __restrict__ Vtab,
    const float* __restrict__ Kmat, const float* __restrict__ lstm_bias,
    const float* __restrict__ pred_W, const float* __restrict__ pred_b,
    const float* __restrict__ score_U, const float* __restrict__ bos,
    float* __restrict__ out, u64w* __restrict__ nh_mb, u64w* __restrict__ pp_mb)
{
  const int blk = blockIdx.x;
  const int s = blk >> 6;      // 0..3 column-split (partners stride 64 -> same XCD %8)
  const int g = blk & 63;      // group id
  const int tid = threadIdx.x;
  const int lane = tid & 63;
  const int wv = tid >> 6;
  const int c = tid & 255;     // my z-column (local)
  const int koff = (tid < 256) ? 0 : 192;
  const int colg = (c >> 6) * H_ + s * 64 + (c & 63);  // global z-column
  const int row0 = g * R_;

  // ---- weight registers: K[koff+i][colg], i = 0..191 ----
  float wreg[192];
  #pragma unroll
  for (int i = 0; i < 192; ++i)
    wreg[i] = Kmat[(size_t)(koff + i) * Z4_ + colg];

  __shared__ float ringVt[R_][4][512];      // 16 KB
  __shared__ float pring[4][R_][DW_];       // 4 KB
  __shared__ float zring[4][R_][256];       // 8 KB (also bos z scratch)
  __shared__ float cring[4][R_][64];        // 2 KB
  __shared__ float zhA[R_][256];            // 2 KB (type-A zh partials)
  __shared__ float zhB[R_][256];            // 2 KB (type-B zh partials)
  __shared__ float zxL[R_][256];            // 2 KB
  __shared__ float predWL[64][128];         // 32 KB (my pred_W slice)
  __shared__ float h1tmp[H_];               // 1 KB (init only)
  __shared__ int   charsL[R_][T_];          // 2 KB
  __shared__ float biasC[256], UL[128], pbL[128];
  __shared__ float scL[R_][L_];
  // LDS relay for deduped polls
  __shared__ float nhLowL[2][64];           // 0.5 KB (w0-relayed nh h[0:64])
  __shared__ float nhUpL[6][64];            // 1.5 KB (w4-relayed nh h[64:256])
  __shared__ int   stampLow, stampUp;

  // ---- one-time loads ----
  if (tid == 0) { stampLow = 0; stampUp = 0; }
  if (tid < 256) biasC[tid] = lstm_bias[(tid >> 6) * H_ + s * 64 + (tid & 63)];
  if (tid < 128) { UL[tid] = score_U[tid]; pbL[tid] = pred_b[tid]; }
  for (int i = tid; i < 64 * 128; i += 512)
    predWL[i >> 7][i & 127] = pred_W[(size_t)(s * 64 + (i >> 7)) * DW_ + (i & 127)];
  for (int i = tid; i < R_ * T_; i += 512)
    charsL[i >> 8][i & 255] = chars[(row0 + (i >> 8)) * T_ + (i & 255)];
  for (int i = tid; i < R_ * 4 * 512; i += 512) ((float*)ringVt)[i] = 0.0f;
  __syncthreads();

  // ---- bos step (x=bos, c0=h0=0): h1/c1, pred0, zh1 ----
  {
    float* zb = &zring[0][0][0];   // 1024-float scratch (slots 0-1)
    for (int c2 = tid; c2 < Z4_; c2 += 512) {
      float a = lstm_bias[c2];
      #pragma unroll 8
      for (int k = 0; k < DC_; ++k) a = fmaf(bos[k], Kmat[(size_t)k * Z4_ + c2], a);
      zb[c2] = a;
    }
    __syncthreads();
    if (tid < H_) {
      float zi = zb[tid], zj = zb[H_ + tid], zo = zb[3 * H_ + tid];
      float nc = sigm(zi) * tanhf(zj);
      float nh = tanhf(nc) * sigm(zo);
      h1tmp[tid] = nh;
      int hl = tid - s * 64;
      if (hl >= 0 && hl < 64) {
        #pragma unroll
        for (int q = 0; q < 4; ++q)
          #pragma unroll
          for (int r = 0; r < R_; ++r) cring[q][r][hl] = nc;
      }
    }
    __syncthreads();
    { // pred0 partials into zhA scratch (512 floats)
      int kq = tid >> 7, e = tid & 127;
      float a = 0.0f;
      #pragma unroll 8
      for (int k = kq * 64; k < kq * 64 + 64; ++k)
        a = fmaf(h1tmp[k], pred_W[(size_t)k * DW_ + e], a);
      ((float*)zhA)[kq * 128 + e] = a;
    }
    __syncthreads();
    if (tid < 128) {
      const float* pa = (const float*)zhA;
      float p = tanhf(pbL[tid] + pa[tid] + pa[128 + tid] + pa[256 + tid] + pa[384 + tid]);
      #pragma unroll
      for (int q = 0; q < 4; ++q)
        #pragma unroll
        for (int r = 0; r < R_; ++r) pring[q][r][tid] = p;
    }
    __syncthreads();   // pred0 partials consumed; zb consumed (h1 extracted)
    { // zh1 = Kh @ h1 via register weights (h1 same for both rows)
      float a = 0.0f;
      if (tid < 256) {
        #pragma unroll
        for (int k = 0; k < 64; ++k) a = fmaf(h1tmp[k], wreg[128 + k], a);
      } else {
        #pragma unroll
        for (int k = 0; k < 192; ++k) a = fmaf(h1tmp[64 + k], wreg[k], a);
      }
      __syncthreads();
      if (tid < 256) zhA[0][c] = a; else zhB[0][c] = a;
    }
    __syncthreads();
    if (tid < 256) {
      float z1 = zhA[0][tid] + zhB[0][tid];
      #pragma unroll
      for (int q = 0; q < 4; ++q)
        #pragma unroll
        for (int r = 0; r < R_; ++r) zring[q][r][tid] = z1;
    }
    __syncthreads();
  }

  // ---- scan ----
  for (int t = 0; t < T_; ++t) {
    const int slot = t & 3;
    const int parR = (t - 1) & 1;
    const int parW = t & 1;
    const unsigned stR = (unsigned)t;
    const unsigned stW = (unsigned)(t + 1);

    // ===== S0: specialized waves =====
    // Vtab gather first (waves 2-3) so the global loads are in flight
    // while the same waves then wait for the nh relay.
    if ((wv >> 1) == 1) {
      int i2 = tid & 127;
      #pragma unroll
      for (int r = 0; r < R_; ++r) {
        const float* vp = Vtab + (size_t)charsL[r][t] * 512;
        #pragma unroll
        for (int q = 0; q < 4; ++q) ringVt[r][slot][q * 128 + i2] = vp[q * 128 + i2];
      }
    }

    if (t > 0) {
      const u64w* nb = nh_mb + ((size_t)parR * G_ + g) * (R_ * H_);
      if (wv < 2) {
        // poll nh first (2 words) -> zh off the pp-wait
        u64w nw0, nw1;
        for (;;) {
          nw0 = ld64(nb + lane);
          nw1 = ld64(nb + H_ + lane);
          int ok = ((unsigned)nw0 == stR) & ((unsigned)nw1 == stR);
          if (__all(ok)) break;
          __builtin_amdgcn_s_sleep(1);
        }
        float nv0 = hi32(nw0), nv1 = hi32(nw1);
        if (wv == 0) {   // relay payloads to w2-3 (exact bits)
          nhLowL[0][lane] = nv0;
          nhLowL[1][lane] = nv1;
          __hip_atomic_store(&stampLow, (int)t, __ATOMIC_RELEASE,
                             __HIP_MEMORY_SCOPE_WORKGROUP);
        }
        // zh(t-1) partial over h[0:64] via register weights (needs only nh)
        float z0 = 0.0f, z1 = 0.0f;
        #pragma unroll
        for (int k = 0; k < 64; ++k) {
          float w = wreg[128 + k];
          z0 = fmaf(bcast(nv0, k), w, z0);
          z1 = fmaf(bcast(nv1, k), w, z1);
        }
        zhA[0][c] = z0; zhA[1][c] = z1;
        // pp poll (partners publish pp ~400cy after nh; usually arrived)
        const u64w* ppb = pp_mb + ((size_t)parR * G_ + g) * (S_ * R_ * 128) + wv * 128;
        u64w pw0[S_], pw1[S_];
        for (;;) {
          #pragma unroll
          for (int sp = 0; sp < S_; ++sp) {
            pw0[sp] = ld64(ppb + (size_t)sp * (R_ * 128) + lane);
            pw1[sp] = ld64(ppb + (size_t)sp * (R_ * 128) + lane + 64);
          }
          int ok = 1;
          #pragma unroll
          for (int sp = 0; sp < S_; ++sp)
            ok &= ((unsigned)pw0[sp] == stR) & ((unsigned)pw1[sp] == stR);
          if (__all(ok)) break;
          __builtin_amdgcn_s_sleep(1);
        }
        // pred(t-1) for row r=wv (sum order = sp 0..3, matches prior rounds)
        float a0 = pbL[lane], a1 = pbL[lane + 64];
        #pragma unroll
        for (int sp = 0; sp < S_; ++sp) {
          a0 += hi32(pw0[sp]);
          a1 += hi32(pw1[sp]);
        }
        int ps = (t - 1) & 3;
        pring[ps][wv][lane] = tanhf(a0);
        pring[ps][wv][lane + 64] = tanhf(a1);
      } else if (wv < 4) {
        // LDS relay wait (no LLC traffic); gather loads already issued
        while (__hip_atomic_load(&stampLow, __ATOMIC_ACQUIRE,
                                 __HIP_MEMORY_SCOPE_WORKGROUP) != (int)t)
          __builtin_amdgcn_s_sleep(1);
        float nv0 = nhLowL[0][lane], nv1 = nhLowL[1][lane];
        float z0 = 0.0f, z1 = 0.0f;
        #pragma unroll
        for (int k = 0; k < 64; ++k) {
          float w = wreg[128 + k];
          z0 = fmaf(bcast(nv0, k), w, z0);
          z1 = fmaf(bcast(nv1, k), w, z1);
        }
        zhA[0][c] = z0; zhA[1][c] = z1;
      } else if (wv == 4) {
        // sole LLC poller for the 6 upper nh words; relay to w5-7
        u64w nw[2][3];
        for (;;) {
          #pragma unroll
          for (int r = 0; r < 2; ++r)
            #pragma unroll
            for (int j = 0; j < 3; ++j)
              nw[r][j] = ld64(nb + (size_t)r * H_ + 64 + j * 64 + lane);
          int ok = 1;
          #pragma unroll
          for (int r = 0; r < 2; ++r)
            #pragma unroll
            for (int j = 0; j < 3; ++j)
              ok &= ((unsigned)nw[r][j] == stR);
          if (__all(ok)) break;
          __builtin_amdgcn_s_sleep(1);
        }
        #pragma unroll
        for (int r = 0; r < 2; ++r)
          #pragma unroll
          for (int j = 0; j < 3; ++j)
            nhUpL[r * 3 + j][lane] = hi32(nw[r][j]);
        __hip_atomic_store(&stampUp, (int)t, __ATOMIC_RELEASE,
                           __HIP_MEMORY_SCOPE_WORKGROUP);
        // zh from register copies (same chain order as all upper waves)
        float a0 = 0.0f, a1 = 0.0f;
        #pragma unroll
        for (int j = 0; j < 3; ++j) {
          float nv0 = hi32(nw[0][j]), nv1 = hi32(nw[1][j]);
          #pragma unroll
          for (int k = 0; k < 64; ++k) {
            float w = wreg[j * 64 + k];
            a0 = fmaf(bcast(nv0, k), w, a0);
            a1 = fmaf(bcast(nv1, k), w, a1);
          }
        }
        zhB[0][c] = a0; zhB[1][c] = a1;
      } else {
        // w5-7: LDS relay wait, then identical zh chain from relayed bits
        while (__hip_atomic_load(&stampUp, __ATOMIC_ACQUIRE,
                                 __HIP_MEMORY_SCOPE_WORKGROUP) != (int)t)
          __builtin_amdgcn_s_sleep(1);
        float a0 = 0.0f, a1 = 0.0f;
        #pragma unroll
        for (int j = 0; j < 3; ++j) {
          float nv0 = nhUpL[j][lane], nv1 = nhUpL[3 + j][lane];
          #pragma unroll
          for (int k = 0; k < 64; ++k) {
            float w = wreg[j * 64 + k];
            a0 = fmaf(bcast(nv0, k), w, a0);
            a1 = fmaf(bcast(nv1, k), w, a1);
          }
        }
        zhB[0][c] = a0; zhB[1][c] = a1;
      }
    }
    __syncthreads();                                   // B1

    // ===== S1: zring(t-1) reduce + scores =====
    if (t > 0) {
      int r = tid >> 8, cc = tid & 255;
      zring[(t - 1) & 3][r][cc] = zhA[r][cc] + zhB[r][cc];
    }
    {
      int r = wv >> 2, w = wv & 3;
      int ps = (t - 1 - w) & 3;
      float il = invlen(w);
      float acc = 0.0f;
      #pragma unroll
      for (int hf = 0; hf < 2; ++hf) {
        int e = lane + hf * 64;
        float sa = 0.0f;
        #pragma unroll
        for (int c2 = 0; c2 < L_; ++c2)
          if (c2 <= w) sa += ringVt[r][(t - c2) & 3][w * 128 + e];
        acc = fmaf(pring[ps][r][e] + UL[e], sa * il, acc);
      }
      #pragma unroll
      for (int off = 32; off; off >>= 1) acc += __shfl_down(acc, off);
      if (lane == 0) scL[r][w] = (w <= t) ? acc : NEGF;
    }
    __syncthreads();                                   // B2

    // ===== S2: vtsel (lanes) + zx via register Kx + outputs =====
    if (tid < 256) {
      float vt0[2], vt1[2];
      #pragma unroll
      for (int r = 0; r < 2; ++r) {
        int bw = amax4(scL[r]);
        float il = invlen(bw);
        float v0 = 0.f, v1 = 0.f;
        #pragma unroll
        for (int c2 = 0; c2 < L_; ++c2)
          if (c2 <= bw) {
            v0 += ringVt[r][(t - c2) & 3][bw * 128 + lane];
            v1 += ringVt[r][(t - c2) & 3][bw * 128 + 64 + lane];
          }
        vt0[r] = v0 * il; vt1[r] = v1 * il;
      }
      float a0 = 0.f, a1 = 0.f;
      #pragma unroll
      for (int k = 0; k < 64; ++k) {
        float w0 = wreg[k], w1 = wreg[64 + k];
        a0 = fmaf(bcast(vt0[0], k), w0, a0);
        a1 = fmaf(bcast(vt0[1], k), w0, a1);
        a0 = fmaf(bcast(vt1[0], k), w1, a0);
        a1 = fmaf(bcast(vt1[1], k), w1, a1);
      }
      zxL[0][c] = a0; zxL[1][c] = a1;
      if (s == 0 && tid < R_) {
        int bw = amax4(scL[tid]);
        out[(row0 + tid) * T_ + t] = scL[tid][bw];
        out[B_ * T_ + (row0 + tid) * T_ + t] = (float)(bw + 1);
      }
    }
    __syncthreads();                                   // B3

    // ===== S3 (waves 0-1): gates -> publish nh; in-wave pp -> publish =====
    // Waves 2-7 race into next step's S0 (stamps self-synchronize).
    if (tid < 128) {
      __builtin_amdgcn_s_setprio(1);
      int r = wv, hl = lane;
      int bw = amax4(scL[r]);
      int zs = (t - 1 - bw) & 3;
      float zg[4];
      #pragma unroll
      for (int gi = 0; gi < 4; ++gi) {
        int cc = gi * 64 + hl;
        zg[gi] = biasC[cc] + zring[zs][r][cc] + zxL[r][cc];
      }
      float cp = cring[zs][r][hl];
      float nc = cp * sigm(zg[2]) + sigm(zg[0]) * tanhf(zg[1]);
      float nh = tanhf(nc) * sigm(zg[3]);
      pub64(&nh_mb[((size_t)parW * G_ + g) * (R_ * H_) + (size_t)r * H_ + s * 64 + hl],
            nh, stW);
      cring[slot][r][hl] = nc;
      // pp partial over my 64 h-rows, in-wave (readlane broadcast + LDS predW)
      float p0 = 0.f, p1 = 0.f;
      #pragma unroll
      for (int kk = 0; kk < 64; ++kk) {
        float nb2 = bcast(nh, kk);
        p0 = fmaf(nb2, predWL[kk][lane], p0);
        p1 = fmaf(nb2, predWL[kk][lane + 64], p1);
      }
      u64w* pb = pp_mb + ((size_t)parW * G_ + g) * (S_ * R_ * 128)
               + (size_t)s * (R_ * 128) + (size_t)r * 128;
      pub64(pb + lane, p0, stW);
      pub64(pb + lane + 64, p1, stW);
      __builtin_amdgcn_s_setprio(0);
    }
    // no barrier: next iteration's B1 re-converges
  }
}

extern "C" void kernel_launch(void* const* d_in, const int* in_sizes, int n_in,
                              void* d_out, int out_size, void* d_ws, size_t ws_size,
                              hipStream_t stream) {
  const int*   chars     = (const int*)d_in[0];
  const float* char_emb  = (const float*)d_in[1];
  const float* reset_W   = (const float*)d_in[2];
  const float* reset_b   = (const float*)d_in[3];
  const float* com_W     = (const float*)d_in[4];
  const float* com_b     = (const float*)d_in[5];
  const float* lstm_k    = (const float*)d_in[6];
  const float* lstm_bias = (const float*)d_in[7];
  const float* pred_W    = (const float*)d_in[8];
  const float* pred_b    = (const float*)d_in[9];
  const float* score_U   = (const float*)d_in[10];
  const float* bos       = (const float*)d_in[11];

  char* ws = (char*)d_ws;
  float* Vtab = (float*)(ws + WS_VTAB);
  u64w* nh_mb = (u64w*)(ws + WS_NH);
  u64w* pp_mb = (u64w*)(ws + WS_PP);
  // No flags, no memset: the 0xAA poison word never matches a stamp in [1,256].

  vtab_kernel<<<V_, 512, 0, stream>>>(char_emb, reset_W, reset_b, com_W, com_b, Vtab);
  seq_kernel<<<256, 512, 0, stream>>>(chars, Vtab, lstm_k, lstm_bias, pred_W,
                                      pred_b, score_U, bos, (float*)d_out,
                                      nh_mb, pp_mb);
}

// Round 8
// 1945.516 us; speedup vs baseline: 1.4911x; 1.0703x over previous
//
#include <hip/hip_runtime.h>

#define B_ 128
#define T_ 256
#define L_ 4
#define DC_ 128
#define DW_ 128
#define H_ 256
#define V_ 6000
#define Z4_ 1024   // 4*H
#define S_ 4       // blocks per group (z-column split)
#define R_ 2       // batch rows per group
#define G_ 64      // groups = B/R
#define NEGF -1e30f

// d_ws layout (bytes). Stamps live inside data words — no flags, no memset.
#define WS_VTAB  4096                          // V*L*DW f32 = 12,288,000
#define WS_NH    (WS_VTAB + V_*L_*DW_*4)       // u64 [2][G][R][H]      = 512 KB
#define WS_PP    (WS_NH + (size_t)2*G_*R_*H_*8)// u64 [2][G][S][R][128] = 1 MB

typedef unsigned long long u64w;

__device__ __forceinline__ float sigm(float x) { return 1.0f / (1.0f + expf(-x)); }
__device__ __forceinline__ void pub64(u64w* p, float v, unsigned stamp) {
  u64w w = ((u64w)__float_as_uint(v) << 32) | (u64w)stamp;
  __hip_atomic_store(p, w, __ATOMIC_RELAXED, __HIP_MEMORY_SCOPE_AGENT);
}
__device__ __forceinline__ u64w ld64(const u64w* p) {
  return __hip_atomic_load(p, __ATOMIC_RELAXED, __HIP_MEMORY_SCOPE_AGENT);
}
__device__ __forceinline__ float hi32(u64w w) {
  return __uint_as_float((unsigned)(w >> 32));
}
// wave-broadcast from lane l via v_readlane (result lands in an SGPR — no VGPR cost)
__device__ __forceinline__ float bcast(float v, int l) {
  return __int_as_float(__builtin_amdgcn_readlane(__float_as_int(v), l));
}
__device__ __forceinline__ int amax4(const float* sc) {   // first-max-wins (jnp.argmax)
  float bs = sc[0]; int bw = 0;
  if (sc[1] > bs) { bs = sc[1]; bw = 1; }
  if (sc[2] > bs) { bs = sc[2]; bw = 2; }
  if (sc[3] > bs) { bs = sc[3]; bw = 3; }
  return bw;
}
__device__ __forceinline__ float invlen(int w) {
  return (w == 0) ? 1.0f : (w == 1) ? 0.5f : (w == 2) ? (1.0f / 3.0f) : 0.25f;
}

// ------------------------------------------------------------------
// Kernel 1: vocab composition table (unchanged — verified).
// ------------------------------------------------------------------
__global__ __launch_bounds__(512) void vtab_kernel(
    const float* __restrict__ char_emb, const float* __restrict__ reset_W,
    const float* __restrict__ reset_b, const float* __restrict__ com_W,
    const float* __restrict__ com_b, float* __restrict__ Vtab)
{
  const int v = blockIdx.x;
  const int tid = threadIdx.x;
  const int w = tid >> 7;
  const int e = tid & 127;
  __shared__ float emb[DC_];
  __shared__ float ge[L_][DC_];
  if (tid < DC_) emb[tid] = char_emb[v * DC_ + tid];
  __syncthreads();
  float acc = reset_b[w * DC_ + e];
  const float* W = reset_W + (size_t)w * DC_ * DC_;
  #pragma unroll 8
  for (int k = 0; k < DC_; ++k) acc = fmaf(emb[k], W[k * DC_ + e], acc);
  ge[w][e] = sigm(acc) * emb[e];
  __syncthreads();
  float acc2 = com_b[e];
  #pragma unroll 8
  for (int k = 0; k < DC_; ++k) acc2 = fmaf(ge[w][k], com_W[k * DW_ + e], acc2);
  Vtab[((size_t)v * L_ + w) * DW_ + e] = tanhf(acc2);
}

// ------------------------------------------------------------------
// Kernel 2: distributed scan, S=4 x R=2, blk = s*64+g, 512 threads.
// R7 verified base (floor 1994us; LDS poll-relay dedup).
// THIS ROUND (R8): remove the S1 phase. Scores for w>=1 depend only
// on previous-step pring/ringVt slots -> computed in S0 by w2-3,
// hidden under the nh-detect wait (c2=0 term re-loaded from Vtab
// into registers, same bits as the gathered copy, so no race with
// the concurrent gather and identical sums). Score (r,0) computed
// by w0/w1 right after they produce pred(t-1) (same-wave ordering).
// zring reduce moves to S2 on threads 256-511 (idle there). Step
// now 3 phases / 2 barriers (was 4/3). Per-pair score arithmetic,
// shuffle-reduce shape, and every accumulation chain unchanged ->
// bit-identical outputs.
// ------------------------------------------------------------------
__global__ __launch_bounds__(512, 2) void seq_kernel(
    const int* __restrict__ chars, const float* __restrict__ Vtab,
    const float* __restrict__ Kmat, const float* __restrict__ lstm_bias,
    const float* __restrict__ pred_W, const float* __restrict__ pred_b,
    const float* __restrict__ score_U, const float* __restrict__ bos,
    float* __restrict__ out, u64w* __restrict__ nh_mb, u64w* __restrict__ pp_mb)
{
  const int blk = blockIdx.x;
  const int s = blk >> 6;      // 0..3 column-split (partners stride 64 -> same XCD %8)
  const int g = blk & 63;      // group id
  const int tid = threadIdx.x;
  const int lane = tid & 63;
  const int wv = tid >> 6;
  const int c = tid & 255;     // my z-column (local)
  const int koff = (tid < 256) ? 0 : 192;
  const int colg = (c >> 6) * H_ + s * 64 + (c & 63);  // global z-column
  const int row0 = g * R_;

  // ---- weight registers: K[koff+i][colg], i = 0..191 ----
  float wreg[192];
  #pragma unroll
  for (int i = 0; i < 192; ++i)
    wreg[i] = Kmat[(size_t)(koff + i) * Z4_ + colg];

  __shared__ float ringVt[R_][4][512];      // 16 KB
  __shared__ float pring[4][R_][DW_];       // 4 KB
  __shared__ float zring[4][R_][256];       // 8 KB (also bos z scratch)
  __shared__ float cring[4][R_][64];        // 2 KB
  __shared__ float zhA[R_][256];            // 2 KB (type-A zh partials)
  __shared__ float zhB[R_][256];            // 2 KB (type-B zh partials)
  __shared__ float zxL[R_][256];            // 2 KB
  __shared__ float predWL[64][128];         // 32 KB (my pred_W slice)
  __shared__ float h1tmp[H_];               // 1 KB (init only)
  __shared__ int   charsL[R_][T_];          // 2 KB
  __shared__ float biasC[256], UL[128], pbL[128];
  __shared__ float scL[R_][L_];
  // LDS relay for deduped polls
  __shared__ float nhLowL[2][64];           // 0.5 KB (w0-relayed nh h[0:64])
  __shared__ float nhUpL[6][64];            // 1.5 KB (w4-relayed nh h[64:256])
  __shared__ int   stampLow, stampUp;

  // ---- one-time loads ----
  if (tid == 0) { stampLow = 0; stampUp = 0; }
  if (tid < 256) biasC[tid] = lstm_bias[(tid >> 6) * H_ + s * 64 + (tid & 63)];
  if (tid < 128) { UL[tid] = score_U[tid]; pbL[tid] = pred_b[tid]; }
  for (int i = tid; i < 64 * 128; i += 512)
    predWL[i >> 7][i & 127] = pred_W[(size_t)(s * 64 + (i >> 7)) * DW_ + (i & 127)];
  for (int i = tid; i < R_ * T_; i += 512)
    charsL[i >> 8][i & 255] = chars[(row0 + (i >> 8)) * T_ + (i & 255)];
  for (int i = tid; i < R_ * 4 * 512; i += 512) ((float*)ringVt)[i] = 0.0f;
  __syncthreads();

  // ---- bos step (x=bos, c0=h0=0): h1/c1, pred0, zh1 ----
  {
    float* zb = &zring[0][0][0];   // 1024-float scratch (slots 0-1)
    for (int c2 = tid; c2 < Z4_; c2 += 512) {
      float a = lstm_bias[c2];
      #pragma unroll 8
      for (int k = 0; k < DC_; ++k) a = fmaf(bos[k], Kmat[(size_t)k * Z4_ + c2], a);
      zb[c2] = a;
    }
    __syncthreads();
    if (tid < H_) {
      float zi = zb[tid], zj = zb[H_ + tid], zo = zb[3 * H_ + tid];
      float nc = sigm(zi) * tanhf(zj);
      float nh = tanhf(nc) * sigm(zo);
      h1tmp[tid] = nh;
      int hl = tid - s * 64;
      if (hl >= 0 && hl < 64) {
        #pragma unroll
        for (int q = 0; q < 4; ++q)
          #pragma unroll
          for (int r = 0; r < R_; ++r) cring[q][r][hl] = nc;
      }
    }
    __syncthreads();
    { // pred0 partials into zhA scratch (512 floats)
      int kq = tid >> 7, e = tid & 127;
      float a = 0.0f;
      #pragma unroll 8
      for (int k = kq * 64; k < kq * 64 + 64; ++k)
        a = fmaf(h1tmp[k], pred_W[(size_t)k * DW_ + e], a);
      ((float*)zhA)[kq * 128 + e] = a;
    }
    __syncthreads();
    if (tid < 128) {
      const float* pa = (const float*)zhA;
      float p = tanhf(pbL[tid] + pa[tid] + pa[128 + tid] + pa[256 + tid] + pa[384 + tid]);
      #pragma unroll
      for (int q = 0; q < 4; ++q)
        #pragma unroll
        for (int r = 0; r < R_; ++r) pring[q][r][tid] = p;
    }
    __syncthreads();   // pred0 partials consumed; zb consumed (h1 extracted)
    { // zh1 = Kh @ h1 via register weights (h1 same for both rows)
      float a = 0.0f;
      if (tid < 256) {
        #pragma unroll
        for (int k = 0; k < 64; ++k) a = fmaf(h1tmp[k], wreg[128 + k], a);
      } else {
        #pragma unroll
        for (int k = 0; k < 192; ++k) a = fmaf(h1tmp[64 + k], wreg[k], a);
      }
      __syncthreads();
      if (tid < 256) zhA[0][c] = a; else zhB[0][c] = a;
    }
    __syncthreads();
    if (tid < 256) {
      float z1 = zhA[0][tid] + zhB[0][tid];
      #pragma unroll
      for (int q = 0; q < 4; ++q)
        #pragma unroll
        for (int r = 0; r < R_; ++r) zring[q][r][tid] = z1;
    }
    __syncthreads();
  }

  // ---- scan ----
  for (int t = 0; t < T_; ++t) {
    const int slot = t & 3;
    const int parR = (t - 1) & 1;
    const int parW = t & 1;
    const unsigned stR = (unsigned)t;
    const unsigned stW = (unsigned)(t + 1);

    // ===== S0: polls + zh partials + pred + ALL scores =====
    if (wv < 2) {
      // w0: nh poll + relay + zhA + pp poll + pred + score (r,0)
      const int r = wv;
      const float* vp0 = Vtab + (size_t)charsL[r][t] * 512;
      float vva = vp0[lane];          // c2=0 term, e=lane   (same bits as gather)
      float vvb = vp0[64 + lane];     // c2=0 term, e=lane+64
      if (t > 0) {
        const u64w* nb = nh_mb + ((size_t)parR * G_ + g) * (R_ * H_);
        u64w nw0, nw1;
        for (;;) {
          nw0 = ld64(nb + lane);
          nw1 = ld64(nb + H_ + lane);
          int ok = ((unsigned)nw0 == stR) & ((unsigned)nw1 == stR);
          if (__all(ok)) break;
          __builtin_amdgcn_s_sleep(1);
        }
        float nv0 = hi32(nw0), nv1 = hi32(nw1);
        if (wv == 0) {   // relay payloads to w2-3 (exact bits)
          nhLowL[0][lane] = nv0;
          nhLowL[1][lane] = nv1;
          __hip_atomic_store(&stampLow, (int)t, __ATOMIC_RELEASE,
                             __HIP_MEMORY_SCOPE_WORKGROUP);
        }
        // zh(t-1) partial over h[0:64] via register weights (needs only nh)
        float z0 = 0.0f, z1 = 0.0f;
        #pragma unroll
        for (int k = 0; k < 64; ++k) {
          float w = wreg[128 + k];
          z0 = fmaf(bcast(nv0, k), w, z0);
          z1 = fmaf(bcast(nv1, k), w, z1);
        }
        zhA[0][c] = z0; zhA[1][c] = z1;
        // pp poll (partners publish pp ~400cy after nh; usually arrived)
        const u64w* ppb = pp_mb + ((size_t)parR * G_ + g) * (S_ * R_ * 128) + wv * 128;
        u64w pw0[S_], pw1[S_];
        for (;;) {
          #pragma unroll
          for (int sp = 0; sp < S_; ++sp) {
            pw0[sp] = ld64(ppb + (size_t)sp * (R_ * 128) + lane);
            pw1[sp] = ld64(ppb + (size_t)sp * (R_ * 128) + lane + 64);
          }
          int ok = 1;
          #pragma unroll
          for (int sp = 0; sp < S_; ++sp)
            ok &= ((unsigned)pw0[sp] == stR) & ((unsigned)pw1[sp] == stR);
          if (__all(ok)) break;
          __builtin_amdgcn_s_sleep(1);
        }
        // pred(t-1) for row r=wv (sum order = sp 0..3, matches prior rounds)
        float a0 = pbL[lane], a1 = pbL[lane + 64];
        #pragma unroll
        for (int sp = 0; sp < S_; ++sp) {
          a0 += hi32(pw0[sp]);
          a1 += hi32(pw1[sp]);
        }
        int ps = (t - 1) & 3;
        pring[ps][wv][lane] = tanhf(a0);
        pring[ps][wv][lane + 64] = tanhf(a1);
      }
      { // score (r, w=0): needs only pring[(t-1)&3][r] (own wave) + vva/vvb
        int ps = (t - 1) & 3;
        float il = invlen(0);
        float acc = 0.0f;
        { float sa = vva;
          acc = fmaf(pring[ps][r][lane] + UL[lane], sa * il, acc); }
        { float sa = vvb;
          acc = fmaf(pring[ps][r][lane + 64] + UL[lane + 64], sa * il, acc); }
        #pragma unroll
        for (int off = 32; off; off >>= 1) acc += __shfl_down(acc, off);
        if (lane == 0) scL[r][0] = acc;    // w=0 <= t always
      }
    } else if (wv < 4) {
      // w2-3: Vt gather (LDS, both rows) + scores (rsc, w=1..3) hidden
      // under the relay wait, then zhA.
      const int rsc = wv - 2;
      int i2 = tid & 127;
      #pragma unroll
      for (int r = 0; r < R_; ++r) {
        const float* vp = Vtab + (size_t)charsL[r][t] * 512;
        #pragma unroll
        for (int q = 0; q < 4; ++q) ringVt[r][slot][q * 128 + i2] = vp[q * 128 + i2];
      }
      // register copies of the c2=0 terms for my score row (same bits)
      const float* vpr = Vtab + (size_t)charsL[rsc][t] * 512;
      float va[3], vb[3];
      #pragma unroll
      for (int w = 1; w <= 3; ++w) {
        va[w - 1] = vpr[w * 128 + lane];
        vb[w - 1] = vpr[w * 128 + 64 + lane];
      }
      // scores (rsc, w=1..3): read only prev-step pring/ringVt slots
      #pragma unroll
      for (int w = 1; w <= 3; ++w) {
        int ps = (t - 1 - w) & 3;
        float il = invlen(w);
        float acc = 0.0f;
        { float sa = va[w - 1];
          #pragma unroll
          for (int c2 = 1; c2 < L_; ++c2)
            if (c2 <= w) sa += ringVt[rsc][(t - c2) & 3][w * 128 + lane];
          acc = fmaf(pring[ps][rsc][lane] + UL[lane], sa * il, acc); }
        { float sa = vb[w - 1];
          #pragma unroll
          for (int c2 = 1; c2 < L_; ++c2)
            if (c2 <= w) sa += ringVt[rsc][(t - c2) & 3][w * 128 + 64 + lane];
          acc = fmaf(pring[ps][rsc][lane + 64] + UL[lane + 64], sa * il, acc); }
        #pragma unroll
        for (int off = 32; off; off >>= 1) acc += __shfl_down(acc, off);
        if (lane == 0) scL[rsc][w] = (w <= t) ? acc : NEGF;
      }
      if (t > 0) {
        // LDS relay wait (no LLC traffic), then zhA
        while (__hip_atomic_load(&stampLow, __ATOMIC_ACQUIRE,
                                 __HIP_MEMORY_SCOPE_WORKGROUP) != (int)t)
          __builtin_amdgcn_s_sleep(1);
        float nv0 = nhLowL[0][lane], nv1 = nhLowL[1][lane];
        float z0 = 0.0f, z1 = 0.0f;
        #pragma unroll
        for (int k = 0; k < 64; ++k) {
          float w = wreg[128 + k];
          z0 = fmaf(bcast(nv0, k), w, z0);
          z1 = fmaf(bcast(nv1, k), w, z1);
        }
        zhA[0][c] = z0; zhA[1][c] = z1;
      }
    } else if (wv == 4) {
      if (t > 0) {
        const u64w* nb = nh_mb + ((size_t)parR * G_ + g) * (R_ * H_);
        // sole LLC poller for the 6 upper nh words; relay to w5-7
        u64w nw[2][3];
        for (;;) {
          #pragma unroll
          for (int r = 0; r < 2; ++r)
            #pragma unroll
            for (int j = 0; j < 3; ++j)
              nw[r][j] = ld64(nb + (size_t)r * H_ + 64 + j * 64 + lane);
          int ok = 1;
          #pragma unroll
          for (int r = 0; r < 2; ++r)
            #pragma unroll
            for (int j = 0; j < 3; ++j)
              ok &= ((unsigned)nw[r][j] == stR);
          if (__all(ok)) break;
          __builtin_amdgcn_s_sleep(1);
        }
        #pragma unroll
        for (int r = 0; r < 2; ++r)
          #pragma unroll
          for (int j = 0; j < 3; ++j)
            nhUpL[r * 3 + j][lane] = hi32(nw[r][j]);
        __hip_atomic_store(&stampUp, (int)t, __ATOMIC_RELEASE,
                           __HIP_MEMORY_SCOPE_WORKGROUP);
        // zh from register copies (same chain order as all upper waves)
        float a0 = 0.0f, a1 = 0.0f;
        #pragma unroll
        for (int j = 0; j < 3; ++j) {
          float nv0 = hi32(nw[0][j]), nv1 = hi32(nw[1][j]);
          #pragma unroll
          for (int k = 0; k < 64; ++k) {
            float w = wreg[j * 64 + k];
            a0 = fmaf(bcast(nv0, k), w, a0);
            a1 = fmaf(bcast(nv1, k), w, a1);
          }
        }
        zhB[0][c] = a0; zhB[1][c] = a1;
      }
    } else {
      if (t > 0) {
        // w5-7: LDS relay wait, then identical zh chain from relayed bits
        while (__hip_atomic_load(&stampUp, __ATOMIC_ACQUIRE,
                                 __HIP_MEMORY_SCOPE_WORKGROUP) != (int)t)
          __builtin_amdgcn_s_sleep(1);
        float a0 = 0.0f, a1 = 0.0f;
        #pragma unroll
        for (int j = 0; j < 3; ++j) {
          float nv0 = nhUpL[j][lane], nv1 = nhUpL[3 + j][lane];
          #pragma unroll
          for (int k = 0; k < 64; ++k) {
            float w = wreg[j * 64 + k];
            a0 = fmaf(bcast(nv0, k), w, a0);
            a1 = fmaf(bcast(nv1, k), w, a1);
          }
        }
        zhB[0][c] = a0; zhB[1][c] = a1;
      }
    }
    __syncthreads();                                   // B1

    // ===== S2': vtsel + zx + outputs (tid<256) | zring reduce (tid>=256) =====
    if (tid < 256) {
      float vt0[2], vt1[2];
      #pragma unroll
      for (int r = 0; r < 2; ++r) {
        int bw = amax4(scL[r]);
        float il = invlen(bw);
        float v0 = 0.f, v1 = 0.f;
        #pragma unroll
        for (int c2 = 0; c2 < L_; ++c2)
          if (c2 <= bw) {
            v0 += ringVt[r][(t - c2) & 3][bw * 128 + lane];
            v1 += ringVt[r][(t - c2) & 3][bw * 128 + 64 + lane];
          }
        vt0[r] = v0 * il; vt1[r] = v1 * il;
      }
      float a0 = 0.f, a1 = 0.f;
      #pragma unroll
      for (int k = 0; k < 64; ++k) {
        float w0 = wreg[k], w1 = wreg[64 + k];
        a0 = fmaf(bcast(vt0[0], k), w0, a0);
        a1 = fmaf(bcast(vt0[1], k), w0, a1);
        a0 = fmaf(bcast(vt1[0], k), w1, a0);
        a1 = fmaf(bcast(vt1[1], k), w1, a1);
      }
      zxL[0][c] = a0; zxL[1][c] = a1;
      if (s == 0 && tid < R_) {
        int bw = amax4(scL[tid]);
        out[(row0 + tid) * T_ + t] = scL[tid][bw];
        out[B_ * T_ + (row0 + tid) * T_ + t] = (float)(bw + 1);
      }
    } else if (t > 0) {
      // zring(t-1) reduce (same values as before, any-thread pure function)
      zring[(t - 1) & 3][0][c] = zhA[0][c] + zhB[0][c];
      zring[(t - 1) & 3][1][c] = zhA[1][c] + zhB[1][c];
    }
    __syncthreads();                                   // B2

    // ===== S3 (waves 0-1): gates -> publish nh; in-wave pp -> publish =====
    // Waves 2-7 race into next step's S0 (stamps self-synchronize).
    if (tid < 128) {
      __builtin_amdgcn_s_setprio(1);
      int r = wv, hl = lane;
      int bw = amax4(scL[r]);
      int zs = (t - 1 - bw) & 3;
      float zg[4];
      #pragma unroll
      for (int gi = 0; gi < 4; ++gi) {
        int cc = gi * 64 + hl;
        zg[gi] = biasC[cc] + zring[zs][r][cc] + zxL[r][cc];
      }
      float cp = cring[zs][r][hl];
      float nc = cp * sigm(zg[2]) + sigm(zg[0]) * tanhf(zg[1]);
      float nh = tanhf(nc) * sigm(zg[3]);
      pub64(&nh_mb[((size_t)parW * G_ + g) * (R_ * H_) + (size_t)r * H_ + s * 64 + hl],
            nh, stW);
      cring[slot][r][hl] = nc;
      // pp partial over my 64 h-rows, in-wave (readlane broadcast + LDS predW)
      float p0 = 0.f, p1 = 0.f;
      #pragma unroll
      for (int kk = 0; kk < 64; ++kk) {
        float nb2 = bcast(nh, kk);
        p0 = fmaf(nb2, predWL[kk][lane], p0);
        p1 = fmaf(nb2, predWL[kk][lane + 64], p1);
      }
      u64w* pb = pp_mb + ((size_t)parW * G_ + g) * (S_ * R_ * 128)
               + (size_t)s * (R_ * 128) + (size_t)r * 128;
      pub64(pb + lane, p0, stW);
      pub64(pb + lane + 64, p1, stW);
      __builtin_amdgcn_s_setprio(0);
    }
    // no barrier: next iteration's B1 re-converges
  }
}

extern "C" void kernel_launch(void* const* d_in, const int* in_sizes, int n_in,
                              void* d_out, int out_size, void* d_ws, size_t ws_size,
                              hipStream_t stream) {
  const int*   chars     = (const int*)d_in[0];
  const float* char_emb  = (const float*)d_in[1];
  const float* reset_W   = (const float*)d_in[2];
  const float* reset_b   = (const float*)d_in[3];
  const float* com_W     = (const float*)d_in[4];
  const float* com_b     = (const float*)d_in[5];
  const float* lstm_k    = (const float*)d_in[6];
  const float* lstm_bias = (const float*)d_in[7];
  const float* pred_W    = (const float*)d_in[8];
  const float* pred_b    = (const float*)d_in[9];
  const float* score_U   = (const float*)d_in[10];
  const float* bos       = (const float*)d_in[11];

  char* ws = (char*)d_ws;
  float* Vtab = (float*)(ws + WS_VTAB);
  u64w* nh_mb = (u64w*)(ws + WS_NH);
  u64w* pp_mb = (u64w*)(ws + WS_PP);
  // No flags, no memset: the 0xAA poison word never matches a stamp in [1,256].

  vtab_kernel<<<V_, 512, 0, stream>>>(char_emb, reset_W, reset_b, com_W, com_b, Vtab);
  seq_kernel<<<256, 512, 0, stream>>>(chars, Vtab, lstm_k, lstm_bias, pred_W,
                                      pred_b, score_U, bos, (float*)d_out,
                                      nh_mb, pp_mb);
}